// Round 5
// baseline (4451.800 us; speedup 1.0000x reference)
//
#include <hip/hip_runtime.h>

#define N_NODES 20000
#define N_EDGES 640000
#define XS 136   // LDS activation row stride in bf16 units (128 + 8 pad)

#define INV_SQRT_AVG 0.0070714082f   // 1/sqrt(19999)
#define INV_AVG      5.000250e-5f    // 1/19999

#define FEATB_OFF 147456             // ushort offset of bf16 feat table in ws (after 9*16384 weights)

typedef __attribute__((ext_vector_type(8))) short bf16x8;
typedef __attribute__((ext_vector_type(4))) float f32x4;
typedef __attribute__((ext_vector_type(2))) float f32x2;

__device__ __forceinline__ ushort f2b(float f) {
  unsigned x = __float_as_uint(f);
  unsigned r = (x + 0x7fffu + ((x >> 16) & 1u)) >> 16;   // RNE
  return (ushort)r;
}
__device__ __forceinline__ float silu(float v) { return v / (1.0f + __expf(-v)); }

__device__ __forceinline__ void pk_atomic_add(float* p, float x, float y) {
#if defined(__has_builtin)
#if __has_builtin(__builtin_amdgcn_global_atomic_fadd_v2f32)
  typedef __attribute__((address_space(1))) f32x2 gf2;
  f32x2 v = {x, y};
  __builtin_amdgcn_global_atomic_fadd_v2f32((gf2*)(unsigned long long)p, v);
  return;
#endif
#endif
  atomicAdd(p, x);
  atomicAdd(p + 1, y);
}

// ---------------- prep: weights f32 [k][n] -> bf16 [n][k]; feat f32 -> bf16 ----
struct PrepArgs { const float* src[9]; };

__global__ __launch_bounds__(256) void prep_kernel(PrepArgs a, ushort* __restrict__ w) {
  int m = blockIdx.y;
  int i = blockIdx.x * 256 + threadIdx.x;   // 0..16383
  int k = i >> 7, n = i & 127;
  w[m * 16384 + n * 128 + k] = f2b(a.src[m][k * 128 + n]);
}

__global__ __launch_bounds__(256) void featcvt_kernel(const float* __restrict__ feat,
                                                      ushort* __restrict__ featb) {
  int i = blockIdx.x * 256 + threadIdx.x;   // exactly 2.56M threads
  featb[i] = f2b(feat[i]);
}

// ---------------- MFMA 64x32x128 per wave ----------------
__device__ __forceinline__ void gemm2(const ushort* X, const ushort* __restrict__ Wn0,
                                      int c, int q, f32x4 acc[4][2]) {
  const int kq = q * 8;
  bf16x8 b[2][4];
#pragma unroll
  for (int ct = 0; ct < 2; ++ct)
#pragma unroll
    for (int ks = 0; ks < 4; ++ks)
      b[ct][ks] = *(const bf16x8*)(Wn0 + (ct * 16 + c) * 128 + ks * 32 + kq);
#pragma unroll
  for (int mt = 0; mt < 4; ++mt)
#pragma unroll
    for (int ks = 0; ks < 4; ++ks) {
      bf16x8 a = *(const bf16x8*)(X + (mt * 16 + c) * XS + ks * 32 + kq);
      acc[mt][0] = __builtin_amdgcn_mfma_f32_16x16x32_bf16(a, b[0][ks], acc[mt][0], 0, 0, 0);
      acc[mt][1] = __builtin_amdgcn_mfma_f32_16x16x32_bf16(a, b[1][ks], acc[mt][1], 0, 0, 0);
    }
}

// stage one bf16 row from global into LDS (4 threads/row, 16B chunks)
__device__ __forceinline__ void stage_copy(ushort* X, const ushort* __restrict__ src,
                                           int row, int sub) {
  const bf16x8* s = (const bf16x8*)src;
  bf16x8* d = (bf16x8*)(X + row * XS);   // 272B row stride, 16B aligned
#pragma unroll
  for (int c2 = 0; c2 < 4; ++c2) d[sub + 4 * c2] = s[sub + 4 * c2];
}

// stage one f32 row (scaled) as bf16 into LDS
__device__ __forceinline__ void stage_cvt(ushort* X, const float* __restrict__ src,
                                          int row, int sub, float scale) {
  const float4* s4 = (const float4*)src + sub * 8;
  uint* d = (uint*)(X + row * XS + sub * 32);
#pragma unroll
  for (int i = 0; i < 8; ++i) {
    float4 v = s4[i];
    d[2 * i]     = (unsigned)f2b(v.x * scale) | ((unsigned)f2b(v.y * scale) << 16);
    d[2 * i + 1] = (unsigned)f2b(v.z * scale) | ((unsigned)f2b(v.w * scale) << 16);
  }
}

// ---------------- edge kernel ----------------
__global__ __launch_bounds__(256, 3) void edge_kernel(
    const float* __restrict__ pos, const ushort* __restrict__ featb,
    const int* __restrict__ snd, const int* __restrict__ rcv,
    const ushort* __restrict__ wq,
    const float* __restrict__ pe_w0, const float* __restrict__ pe_b0,
    const float* __restrict__ pe_b1,
    const float* __restrict__ px_b0, const float* __restrict__ px_b1,
    const float* __restrict__ px_out_w, const float* __restrict__ px_out_b,
    const float* __restrict__ e_w, const float* __restrict__ e_b,
    float* __restrict__ outv, float* __restrict__ outf) {
  __shared__ ushort XA[64 * XS];
  __shared__ ushort XB[64 * XS];
  __shared__ float lenf[64], gp[64], pp[64], egl[64];
  __shared__ float vec3[64][3];
  __shared__ int erc[64];

  const int tid = threadIdx.x;
  const int e0 = blockIdx.x * 64;
  const int lane = tid & 63;
  const int wv = tid >> 6;
  const int c = lane & 15, q = lane >> 4;
  const int n0 = wv * 32;
  const int col0 = n0 + c, col1 = col0 + 16;

  if (tid < 64) {
    int s = snd[e0 + tid], r = rcv[e0 + tid];
    erc[tid] = r;
    float vx = pos[r * 3 + 0] - pos[s * 3 + 0];
    float vy = pos[r * 3 + 1] - pos[s * 3 + 1];
    float vz = pos[r * 3 + 2] - pos[s * 3 + 2];
    float n2 = vx * vx + vy * vy + vz * vz;
    float L = (n2 > 0.0f) ? sqrtf(n2) : 0.0f;
    vec3[tid][0] = vx; vec3[tid][1] = vy; vec3[tid][2] = vz;
    lenf[tid] = L; gp[tid] = 0.0f; pp[tid] = 0.0f;
  }
  {
    int row = tid >> 2, sub = tid & 3;
    stage_copy(XA, featb + (size_t)snd[e0 + row] * 128, row, sub);
    stage_copy(XB, featb + (size_t)rcv[e0 + row] * 128, row, sub);
  }
  __syncthreads();

  const f32x4 z4 = {0.f, 0.f, 0.f, 0.f};
  f32x4 acc[4][2];
#pragma unroll
  for (int mt = 0; mt < 4; ++mt) { acc[mt][0] = z4; acc[mt][1] = z4; }

  // ---- phi_e layer 0 ----
  gemm2(XA, wq + 0 * 16384 + n0 * 128, c, q, acc);
  gemm2(XB, wq + 1 * 16384 + n0 * 128, c, q, acc);
  __syncthreads();
  {
    float b0 = pe_b0[col0], b1 = pe_b0[col1];
    float w0 = pe_w0[256 * 128 + col0], w1 = pe_w0[256 * 128 + col1];
#pragma unroll
    for (int mt = 0; mt < 4; ++mt)
#pragma unroll
      for (int rg = 0; rg < 4; ++rg) {
        int row = mt * 16 + q * 4 + rg;
        float L = lenf[row];
        XA[row * XS + col0] = f2b(silu(acc[mt][0][rg] + L * w0 + b0));
        XA[row * XS + col1] = f2b(silu(acc[mt][1][rg] + L * w1 + b1));
      }
  }
  __syncthreads();

  // ---- phi_e layer 1: XA -> m (single silu pass: gate dot + store to XB) ----
#pragma unroll
  for (int mt = 0; mt < 4; ++mt) { acc[mt][0] = z4; acc[mt][1] = z4; }
  gemm2(XA, wq + 2 * 16384 + n0 * 128, c, q, acc);
  {
    float b0 = pe_b1[col0], b1 = pe_b1[col1];
    float ew0 = e_w[col0], ew1 = e_w[col1];
#pragma unroll
    for (int mt = 0; mt < 4; ++mt)
#pragma unroll
      for (int rg = 0; rg < 4; ++rg) {
        int row = mt * 16 + q * 4 + rg;
        float m0 = silu(acc[mt][0][rg] + b0);
        float m1 = silu(acc[mt][1][rg] + b1);
        XB[row * XS + col0] = f2b(m0);
        XB[row * XS + col1] = f2b(m1);
        float rp = m0 * ew0 + m1 * ew1;
        rp += __shfl_xor(rp, 1); rp += __shfl_xor(rp, 2);
        rp += __shfl_xor(rp, 4); rp += __shfl_xor(rp, 8);
        if (c == 0) atomicAdd(&gp[row], rp);
      }
  }
  __syncthreads();
  if (tid < 64) egl[tid] = 1.0f / (1.0f + __expf(-(gp[tid] + e_b[0])));
  __syncthreads();

  // ---- phi_x layer 0 (MFMA) + gated m_i packed atomics (from XB) ----
#pragma unroll
  for (int mt = 0; mt < 4; ++mt) { acc[mt][0] = z4; acc[mt][1] = z4; }
  gemm2(XB, wq + 3 * 16384 + n0 * 128, c, q, acc);
  {
    int row = tid >> 2, sub = tid & 3;
    float eg = egl[row];
    float* dst = outf + (size_t)erc[row] * 128 + sub * 32;
    const uint* src = (const uint*)(XB + row * XS + sub * 32);
#pragma unroll
    for (int i = 0; i < 16; ++i) {
      uint u = src[i];
      float x = __uint_as_float(u << 16) * eg;
      float y = __uint_as_float(u & 0xffff0000u) * eg;
      pk_atomic_add(dst + 2 * i, x, y);
    }
  }
  {
    float b0 = px_b0[col0], b1 = px_b0[col1];
#pragma unroll
    for (int mt = 0; mt < 4; ++mt)
#pragma unroll
      for (int rg = 0; rg < 4; ++rg) {
        int row = mt * 16 + q * 4 + rg;
        XA[row * XS + col0] = f2b(silu(acc[mt][0][rg] + b0));
        XA[row * XS + col1] = f2b(silu(acc[mt][1][rg] + b1));
      }
  }
  __syncthreads();

  // ---- phi_x layer 1: XA -> Dense(1) tail ----
#pragma unroll
  for (int mt = 0; mt < 4; ++mt) { acc[mt][0] = z4; acc[mt][1] = z4; }
  gemm2(XA, wq + 4 * 16384 + n0 * 128, c, q, acc);
  {
    float b0 = px_b1[col0], b1 = px_b1[col1];
    float pw0 = px_out_w[col0], pw1 = px_out_w[col1];
#pragma unroll
    for (int mt = 0; mt < 4; ++mt)
#pragma unroll
      for (int rg = 0; rg < 4; ++rg) {
        float rp = silu(acc[mt][0][rg] + b0) * pw0 + silu(acc[mt][1][rg] + b1) * pw1;
        rp += __shfl_xor(rp, 1); rp += __shfl_xor(rp, 2);
        rp += __shfl_xor(rp, 4); rp += __shfl_xor(rp, 8);
        if (c == 0) atomicAdd(&pp[mt * 16 + q * 4 + rg], rp);
      }
  }
  __syncthreads();
  if (tid < 192) {
    int ee = tid / 3, cc = tid - ee * 3;
    float phi = pp[ee] + px_out_b[0];
    float sh = phi * vec3[ee][cc] / (1.0f + lenf[ee]);
    atomicAdd(&outv[(size_t)erc[ee] * 3 + cc], sh);
  }
}

// ---------------- node kernel ----------------
__global__ __launch_bounds__(256, 3) void node_kernel(
    const float* __restrict__ pos, const float* __restrict__ feat,
    const ushort* __restrict__ featb, const ushort* __restrict__ wq,
    const float* __restrict__ ph_b0, const float* __restrict__ ph_b1,
    const float* __restrict__ ph_b2,
    float* __restrict__ outv, float* __restrict__ outf) {
  __shared__ ushort XA[64 * XS];
  __shared__ ushort XB[64 * XS];

  const int tid = threadIdx.x;
  const int nb0 = blockIdx.x * 64;
  const int lane = tid & 63;
  const int wv = tid >> 6;
  const int c = lane & 15, q = lane >> 4;
  const int n0 = wv * 32;
  const int col0 = n0 + c, col1 = col0 + 16;

  {
    int row = tid >> 2, sub = tid & 3;
    int nn = nb0 + row; if (nn >= N_NODES) nn = N_NODES - 1;
    stage_cvt(XA, outf + (size_t)nn * 128, row, sub, INV_SQRT_AVG);  // m_i
    stage_copy(XB, featb + (size_t)nn * 128, row, sub);
  }
  __syncthreads();

  const f32x4 z4 = {0.f, 0.f, 0.f, 0.f};
  f32x4 acc[4][2];
#pragma unroll
  for (int mt = 0; mt < 4; ++mt) { acc[mt][0] = z4; acc[mt][1] = z4; }

  // ---- ph layer 0: [m_i | feat] ----
  gemm2(XA, wq + 5 * 16384 + n0 * 128, c, q, acc);
  gemm2(XB, wq + 6 * 16384 + n0 * 128, c, q, acc);
  __syncthreads();
  {
    float b0 = ph_b0[col0], b1 = ph_b0[col1];
#pragma unroll
    for (int mt = 0; mt < 4; ++mt)
#pragma unroll
      for (int rg = 0; rg < 4; ++rg) {
        int row = mt * 16 + q * 4 + rg;
        XA[row * XS + col0] = f2b(silu(acc[mt][0][rg] + b0));
        XA[row * XS + col1] = f2b(silu(acc[mt][1][rg] + b1));
      }
  }
  __syncthreads();

  // ---- ph layer 1: XA -> XB ----
#pragma unroll
  for (int mt = 0; mt < 4; ++mt) { acc[mt][0] = z4; acc[mt][1] = z4; }
  gemm2(XA, wq + 7 * 16384 + n0 * 128, c, q, acc);
  __syncthreads();   // XB reads (layer-0 gemm) are long done; sync before overwrite
  {
    float b0 = ph_b1[col0], b1 = ph_b1[col1];
#pragma unroll
    for (int mt = 0; mt < 4; ++mt)
#pragma unroll
      for (int rg = 0; rg < 4; ++rg) {
        int row = mt * 16 + q * 4 + rg;
        XB[row * XS + col0] = f2b(silu(acc[mt][0][rg] + b0));
        XB[row * XS + col1] = f2b(silu(acc[mt][1][rg] + b1));
      }
  }
  __syncthreads();

  // ---- ph layer 2 (no act) + residual ----
#pragma unroll
  for (int mt = 0; mt < 4; ++mt) { acc[mt][0] = z4; acc[mt][1] = z4; }
  gemm2(XB, wq + 8 * 16384 + n0 * 128, c, q, acc);
  {
    float b0 = ph_b2[col0], b1 = ph_b2[col1];
#pragma unroll
    for (int mt = 0; mt < 4; ++mt)
#pragma unroll
      for (int rg = 0; rg < 4; ++rg) {
        int row = mt * 16 + q * 4 + rg;
        int nn = nb0 + row;
        if (nn < N_NODES) {
          size_t o = (size_t)nn * 128;
          outf[o + col0] = acc[mt][0][rg] + b0 + feat[o + col0];
          outf[o + col1] = acc[mt][1][rg] + b1 + feat[o + col1];
        }
      }
  }
  if (tid < 192) {
    int nl = tid / 3, cc = tid - nl * 3;
    int nn = nb0 + nl;
    if (nn < N_NODES)
      outv[nn * 3 + cc] = pos[nn * 3 + cc] + outv[nn * 3 + cc] * INV_AVG;
  }
}

// ---------------- launch ----------------
extern "C" void kernel_launch(void* const* d_in, const int* in_sizes, int n_in,
                              void* d_out, int out_size, void* d_ws, size_t ws_size,
                              hipStream_t stream) {
  const float* pos  = (const float*)d_in[0];
  const float* feat = (const float*)d_in[1];
  const float* pe_w0 = (const float*)d_in[2];
  const float* pe_b0 = (const float*)d_in[3];
  const float* pe_w1 = (const float*)d_in[4];
  const float* pe_b1 = (const float*)d_in[5];
  const float* px_w0 = (const float*)d_in[6];
  const float* px_b0 = (const float*)d_in[7];
  const float* px_w1 = (const float*)d_in[8];
  const float* px_b1 = (const float*)d_in[9];
  const float* px_out_w = (const float*)d_in[10];
  const float* px_out_b = (const float*)d_in[11];
  const float* e_w = (const float*)d_in[12];
  const float* e_b = (const float*)d_in[13];
  const float* ph_b0 = (const float*)d_in[15];
  const float* ph_b1 = (const float*)d_in[17];
  const float* ph_b2 = (const float*)d_in[19];
  const int* snd = (const int*)d_in[20];
  const int* rcv = (const int*)d_in[21];
  ushort* wq = (ushort*)d_ws;
  ushort* featb = wq + FEATB_OFF;
  float* out = (float*)d_out;

  // d_out doubles as accumulator (m_i in features region, shifts in vectors region)
  hipMemsetAsync(d_out, 0, (size_t)out_size * sizeof(float), stream);

  PrepArgs a;
  a.src[0] = pe_w0;
  a.src[1] = pe_w0 + 128 * 128;
  a.src[2] = pe_w1;
  a.src[3] = px_w0;
  a.src[4] = px_w1;
  a.src[5] = (const float*)d_in[14];              // ph_w0 (m_i half)
  a.src[6] = (const float*)d_in[14] + 128 * 128;  // ph_w0 (feat half)
  a.src[7] = (const float*)d_in[16];              // ph_w1
  a.src[8] = (const float*)d_in[18];              // ph_w2
  prep_kernel<<<dim3(64, 9), 256, 0, stream>>>(a, wq);
  featcvt_kernel<<<(N_NODES * 128) / 256, 256, 0, stream>>>(feat, featb);

  edge_kernel<<<N_EDGES / 64, 256, 0, stream>>>(
      pos, featb, snd, rcv, wq,
      pe_w0, pe_b0, pe_b1, px_b0, px_b1,
      px_out_w, px_out_b, e_w, e_b,
      out, out + 60000);

  node_kernel<<<(N_NODES + 63) / 64, 256, 0, stream>>>(
      pos, feat, featb, wq, ph_b0, ph_b1, ph_b2,
      out, out + 60000);
}

// Round 6
// 4434.906 us; speedup vs baseline: 1.0038x; 1.0038x over previous
//
#include <hip/hip_runtime.h>

#define N_NODES 20000
#define N_EDGES 640000
#define XS 136   // LDS activation row stride in bf16 units (128 + 8 pad)

#define INV_SQRT_AVG 0.0070714082f   // 1/sqrt(19999)
#define INV_AVG      5.000250e-5f    // 1/19999

#define FEATB_OFF 147456             // ushort offset of bf16 feat table in ws (after 9*16384 weights)

typedef __attribute__((ext_vector_type(8))) short bf16x8;
typedef __attribute__((ext_vector_type(4))) float f32x4;

__device__ __forceinline__ ushort f2b(float f) {
  unsigned x = __float_as_uint(f);
  unsigned r = (x + 0x7fffu + ((x >> 16) & 1u)) >> 16;   // RNE
  return (ushort)r;
}
__device__ __forceinline__ float silu(float v) { return v / (1.0f + __expf(-v)); }

// ---------------- prep: weights f32 [k][n] -> bf16 [n][k]; feat f32 -> bf16 ----
struct PrepArgs { const float* src[9]; };

__global__ __launch_bounds__(256) void prep_kernel(PrepArgs a, ushort* __restrict__ w) {
  int m = blockIdx.y;
  int i = blockIdx.x * 256 + threadIdx.x;   // 0..16383
  int k = i >> 7, n = i & 127;
  w[m * 16384 + n * 128 + k] = f2b(a.src[m][k * 128 + n]);
}

__global__ __launch_bounds__(256) void featcvt_kernel(const float* __restrict__ feat,
                                                      ushort* __restrict__ featb) {
  int i = blockIdx.x * 256 + threadIdx.x;   // exactly 2.56M threads
  featb[i] = f2b(feat[i]);
}

// ---------------- MFMA 64x32x128 per wave ----------------
__device__ __forceinline__ void gemm2(const ushort* X, const ushort* __restrict__ Wn0,
                                      int c, int q, f32x4 acc[4][2]) {
  const int kq = q * 8;
  bf16x8 b[2][4];
#pragma unroll
  for (int ct = 0; ct < 2; ++ct)
#pragma unroll
    for (int ks = 0; ks < 4; ++ks)
      b[ct][ks] = *(const bf16x8*)(Wn0 + (ct * 16 + c) * 128 + ks * 32 + kq);
#pragma unroll
  for (int mt = 0; mt < 4; ++mt)
#pragma unroll
    for (int ks = 0; ks < 4; ++ks) {
      bf16x8 a = *(const bf16x8*)(X + (mt * 16 + c) * XS + ks * 32 + kq);
      acc[mt][0] = __builtin_amdgcn_mfma_f32_16x16x32_bf16(a, b[0][ks], acc[mt][0], 0, 0, 0);
      acc[mt][1] = __builtin_amdgcn_mfma_f32_16x16x32_bf16(a, b[1][ks], acc[mt][1], 0, 0, 0);
    }
}

// stage one bf16 row from global into LDS (4 threads/row, 16B chunks)
__device__ __forceinline__ void stage_copy(ushort* X, const ushort* __restrict__ src,
                                           int row, int sub) {
  const bf16x8* s = (const bf16x8*)src;
  bf16x8* d = (bf16x8*)(X + row * XS);   // 272B row stride, 16B aligned
#pragma unroll
  for (int c2 = 0; c2 < 4; ++c2) d[sub + 4 * c2] = s[sub + 4 * c2];
}

// stage one f32 row (scaled) as bf16 into LDS
__device__ __forceinline__ void stage_cvt(ushort* X, const float* __restrict__ src,
                                          int row, int sub, float scale) {
  const float4* s4 = (const float4*)src + sub * 8;
  uint* d = (uint*)(X + row * XS + sub * 32);
#pragma unroll
  for (int i = 0; i < 8; ++i) {
    float4 v = s4[i];
    d[2 * i]     = (unsigned)f2b(v.x * scale) | ((unsigned)f2b(v.y * scale) << 16);
    d[2 * i + 1] = (unsigned)f2b(v.z * scale) | ((unsigned)f2b(v.w * scale) << 16);
  }
}

// ---------------- edge kernel ----------------
__global__ __launch_bounds__(256, 3) void edge_kernel(
    const float* __restrict__ pos, const ushort* __restrict__ featb,
    const int* __restrict__ snd, const int* __restrict__ rcv,
    const ushort* __restrict__ wq,
    const float* __restrict__ pe_w0, const float* __restrict__ pe_b0,
    const float* __restrict__ pe_b1,
    const float* __restrict__ px_b0, const float* __restrict__ px_b1,
    const float* __restrict__ px_out_w, const float* __restrict__ px_out_b,
    const float* __restrict__ e_w, const float* __restrict__ e_b,
    float* __restrict__ outv, float* __restrict__ outf) {
  __shared__ ushort XA[64 * XS];
  __shared__ ushort XB[64 * XS];
  __shared__ float lenf[64], gp[64], pp[64], egl[64];
  __shared__ float vec3[64][3];
  __shared__ int erc[64];

  const int tid = threadIdx.x;
  const int e0 = blockIdx.x * 64;
  const int lane = tid & 63;
  const int wv = tid >> 6;
  const int c = lane & 15, q = lane >> 4;
  const int n0 = wv * 32;
  const int col0 = n0 + c, col1 = col0 + 16;

  if (tid < 64) {
    int s = snd[e0 + tid], r = rcv[e0 + tid];
    erc[tid] = r;
    float vx = pos[r * 3 + 0] - pos[s * 3 + 0];
    float vy = pos[r * 3 + 1] - pos[s * 3 + 1];
    float vz = pos[r * 3 + 2] - pos[s * 3 + 2];
    float n2 = vx * vx + vy * vy + vz * vz;
    float L = (n2 > 0.0f) ? sqrtf(n2) : 0.0f;
    vec3[tid][0] = vx; vec3[tid][1] = vy; vec3[tid][2] = vz;
    lenf[tid] = L; gp[tid] = 0.0f; pp[tid] = 0.0f;
  }
  {
    int row = tid >> 2, sub = tid & 3;
    stage_copy(XA, featb + (size_t)snd[e0 + row] * 128, row, sub);
    stage_copy(XB, featb + (size_t)rcv[e0 + row] * 128, row, sub);
  }
  __syncthreads();

  const f32x4 z4 = {0.f, 0.f, 0.f, 0.f};
  f32x4 acc[4][2];
#pragma unroll
  for (int mt = 0; mt < 4; ++mt) { acc[mt][0] = z4; acc[mt][1] = z4; }

  // ---- phi_e layer 0 ----
  gemm2(XA, wq + 0 * 16384 + n0 * 128, c, q, acc);
  gemm2(XB, wq + 1 * 16384 + n0 * 128, c, q, acc);
  __syncthreads();
  {
    float b0 = pe_b0[col0], b1 = pe_b0[col1];
    float w0 = pe_w0[256 * 128 + col0], w1 = pe_w0[256 * 128 + col1];
#pragma unroll
    for (int mt = 0; mt < 4; ++mt)
#pragma unroll
      for (int rg = 0; rg < 4; ++rg) {
        int row = mt * 16 + q * 4 + rg;
        float L = lenf[row];
        XA[row * XS + col0] = f2b(silu(acc[mt][0][rg] + L * w0 + b0));
        XA[row * XS + col1] = f2b(silu(acc[mt][1][rg] + L * w1 + b1));
      }
  }
  __syncthreads();

  // ---- phi_e layer 1: XA -> m (single silu pass: store to XB + gate dot) ----
#pragma unroll
  for (int mt = 0; mt < 4; ++mt) { acc[mt][0] = z4; acc[mt][1] = z4; }
  gemm2(XA, wq + 2 * 16384 + n0 * 128, c, q, acc);
  {
    float b0 = pe_b1[col0], b1 = pe_b1[col1];
    float ew0 = e_w[col0], ew1 = e_w[col1];
#pragma unroll
    for (int mt = 0; mt < 4; ++mt)
#pragma unroll
      for (int rg = 0; rg < 4; ++rg) {
        int row = mt * 16 + q * 4 + rg;
        float m0 = silu(acc[mt][0][rg] + b0);
        float m1 = silu(acc[mt][1][rg] + b1);
        XB[row * XS + col0] = f2b(m0);
        XB[row * XS + col1] = f2b(m1);
        float rp = m0 * ew0 + m1 * ew1;
        rp += __shfl_xor(rp, 1); rp += __shfl_xor(rp, 2);
        rp += __shfl_xor(rp, 4); rp += __shfl_xor(rp, 8);
        if (c == 0) atomicAdd(&gp[row], rp);
      }
  }
  __syncthreads();
  if (tid < 64) egl[tid] = 1.0f / (1.0f + __expf(-(gp[tid] + e_b[0])));
  __syncthreads();

  // ---- gated m_i scalar atomics (native global_atomic_add_f32), then phi_x L0 ----
  {
    int row = tid >> 2, sub = tid & 3;
    float eg = egl[row];
    float* dst = outf + (size_t)erc[row] * 128 + sub * 32;
    const uint* src = (const uint*)(XB + row * XS + sub * 32);
#pragma unroll
    for (int i = 0; i < 16; ++i) {
      uint u = src[i];
      atomicAdd(dst + 2 * i,     __uint_as_float(u << 16) * eg);
      atomicAdd(dst + 2 * i + 1, __uint_as_float(u & 0xffff0000u) * eg);
    }
  }
#pragma unroll
  for (int mt = 0; mt < 4; ++mt) { acc[mt][0] = z4; acc[mt][1] = z4; }
  gemm2(XB, wq + 3 * 16384 + n0 * 128, c, q, acc);
  {
    float b0 = px_b0[col0], b1 = px_b0[col1];
#pragma unroll
    for (int mt = 0; mt < 4; ++mt)
#pragma unroll
      for (int rg = 0; rg < 4; ++rg) {
        int row = mt * 16 + q * 4 + rg;
        XA[row * XS + col0] = f2b(silu(acc[mt][0][rg] + b0));
        XA[row * XS + col1] = f2b(silu(acc[mt][1][rg] + b1));
      }
  }
  __syncthreads();

  // ---- phi_x layer 1: XA -> Dense(1) tail ----
#pragma unroll
  for (int mt = 0; mt < 4; ++mt) { acc[mt][0] = z4; acc[mt][1] = z4; }
  gemm2(XA, wq + 4 * 16384 + n0 * 128, c, q, acc);
  {
    float b0 = px_b1[col0], b1 = px_b1[col1];
    float pw0 = px_out_w[col0], pw1 = px_out_w[col1];
#pragma unroll
    for (int mt = 0; mt < 4; ++mt)
#pragma unroll
      for (int rg = 0; rg < 4; ++rg) {
        float rp = silu(acc[mt][0][rg] + b0) * pw0 + silu(acc[mt][1][rg] + b1) * pw1;
        rp += __shfl_xor(rp, 1); rp += __shfl_xor(rp, 2);
        rp += __shfl_xor(rp, 4); rp += __shfl_xor(rp, 8);
        if (c == 0) atomicAdd(&pp[mt * 16 + q * 4 + rg], rp);
      }
  }
  __syncthreads();
  if (tid < 192) {
    int ee = tid / 3, cc = tid - ee * 3;
    float phi = pp[ee] + px_out_b[0];
    float sh = phi * vec3[ee][cc] / (1.0f + lenf[ee]);
    atomicAdd(&outv[(size_t)erc[ee] * 3 + cc], sh);
  }
}

// ---------------- node kernel ----------------
__global__ __launch_bounds__(256, 3) void node_kernel(
    const float* __restrict__ pos, const float* __restrict__ feat,
    const ushort* __restrict__ featb, const ushort* __restrict__ wq,
    const float* __restrict__ ph_b0, const float* __restrict__ ph_b1,
    const float* __restrict__ ph_b2,
    float* __restrict__ outv, float* __restrict__ outf) {
  __shared__ ushort XA[64 * XS];
  __shared__ ushort XB[64 * XS];

  const int tid = threadIdx.x;
  const int nb0 = blockIdx.x * 64;
  const int lane = tid & 63;
  const int wv = tid >> 6;
  const int c = lane & 15, q = lane >> 4;
  const int n0 = wv * 32;
  const int col0 = n0 + c, col1 = col0 + 16;

  {
    int row = tid >> 2, sub = tid & 3;
    int nn = nb0 + row; if (nn >= N_NODES) nn = N_NODES - 1;
    stage_cvt(XA, outf + (size_t)nn * 128, row, sub, INV_SQRT_AVG);  // m_i
    stage_copy(XB, featb + (size_t)nn * 128, row, sub);
  }
  __syncthreads();

  const f32x4 z4 = {0.f, 0.f, 0.f, 0.f};
  f32x4 acc[4][2];
#pragma unroll
  for (int mt = 0; mt < 4; ++mt) { acc[mt][0] = z4; acc[mt][1] = z4; }

  // ---- ph layer 0: [m_i | feat] ----
  gemm2(XA, wq + 5 * 16384 + n0 * 128, c, q, acc);
  gemm2(XB, wq + 6 * 16384 + n0 * 128, c, q, acc);
  __syncthreads();
  {
    float b0 = ph_b0[col0], b1 = ph_b0[col1];
#pragma unroll
    for (int mt = 0; mt < 4; ++mt)
#pragma unroll
      for (int rg = 0; rg < 4; ++rg) {
        int row = mt * 16 + q * 4 + rg;
        XA[row * XS + col0] = f2b(silu(acc[mt][0][rg] + b0));
        XA[row * XS + col1] = f2b(silu(acc[mt][1][rg] + b1));
      }
  }
  __syncthreads();

  // ---- ph layer 1: XA -> XB ----
#pragma unroll
  for (int mt = 0; mt < 4; ++mt) { acc[mt][0] = z4; acc[mt][1] = z4; }
  gemm2(XA, wq + 7 * 16384 + n0 * 128, c, q, acc);
  __syncthreads();
  {
    float b0 = ph_b1[col0], b1 = ph_b1[col1];
#pragma unroll
    for (int mt = 0; mt < 4; ++mt)
#pragma unroll
      for (int rg = 0; rg < 4; ++rg) {
        int row = mt * 16 + q * 4 + rg;
        XB[row * XS + col0] = f2b(silu(acc[mt][0][rg] + b0));
        XB[row * XS + col1] = f2b(silu(acc[mt][1][rg] + b1));
      }
  }
  __syncthreads();

  // ---- ph layer 2 (no act) + residual ----
#pragma unroll
  for (int mt = 0; mt < 4; ++mt) { acc[mt][0] = z4; acc[mt][1] = z4; }
  gemm2(XB, wq + 8 * 16384 + n0 * 128, c, q, acc);
  {
    float b0 = ph_b2[col0], b1 = ph_b2[col1];
#pragma unroll
    for (int mt = 0; mt < 4; ++mt)
#pragma unroll
      for (int rg = 0; rg < 4; ++rg) {
        int row = mt * 16 + q * 4 + rg;
        int nn = nb0 + row;
        if (nn < N_NODES) {
          size_t o = (size_t)nn * 128;
          outf[o + col0] = acc[mt][0][rg] + b0 + feat[o + col0];
          outf[o + col1] = acc[mt][1][rg] + b1 + feat[o + col1];
        }
      }
  }
  if (tid < 192) {
    int nl = tid / 3, cc = tid - nl * 3;
    int nn = nb0 + nl;
    if (nn < N_NODES)
      outv[nn * 3 + cc] = pos[nn * 3 + cc] + outv[nn * 3 + cc] * INV_AVG;
  }
}

// ---------------- launch ----------------
extern "C" void kernel_launch(void* const* d_in, const int* in_sizes, int n_in,
                              void* d_out, int out_size, void* d_ws, size_t ws_size,
                              hipStream_t stream) {
  const float* pos  = (const float*)d_in[0];
  const float* feat = (const float*)d_in[1];
  const float* pe_w0 = (const float*)d_in[2];
  const float* pe_b0 = (const float*)d_in[3];
  const float* pe_b1 = (const float*)d_in[5];
  const float* px_b0 = (const float*)d_in[7];
  const float* px_b1 = (const float*)d_in[9];
  const float* px_out_w = (const float*)d_in[10];
  const float* px_out_b = (const float*)d_in[11];
  const float* e_w = (const float*)d_in[12];
  const float* e_b = (const float*)d_in[13];
  const float* ph_b0 = (const float*)d_in[15];
  const float* ph_b1 = (const float*)d_in[17];
  const float* ph_b2 = (const float*)d_in[19];
  const int* snd = (const int*)d_in[20];
  const int* rcv = (const int*)d_in[21];
  ushort* wq = (ushort*)d_ws;
  ushort* featb = wq + FEATB_OFF;
  float* out = (float*)d_out;

  // d_out doubles as accumulator (m_i in features region, shifts in vectors region)
  hipMemsetAsync(d_out, 0, (size_t)out_size * sizeof(float), stream);

  PrepArgs a;
  a.src[0] = pe_w0;
  a.src[1] = pe_w0 + 128 * 128;
  a.src[2] = (const float*)d_in[4];               // pe_w1
  a.src[3] = (const float*)d_in[6];               // px_w0
  a.src[4] = (const float*)d_in[8];               // px_w1
  a.src[5] = (const float*)d_in[14];              // ph_w0 (m_i half)
  a.src[6] = (const float*)d_in[14] + 128 * 128;  // ph_w0 (feat half)
  a.src[7] = (const float*)d_in[16];              // ph_w1
  a.src[8] = (const float*)d_in[18];              // ph_w2
  prep_kernel<<<dim3(64, 9), 256, 0, stream>>>(a, wq);
  featcvt_kernel<<<(N_NODES * 128) / 256, 256, 0, stream>>>(feat, featb);

  edge_kernel<<<N_EDGES / 64, 256, 0, stream>>>(
      pos, featb, snd, rcv, wq,
      pe_w0, pe_b0, pe_b1, px_b0, px_b1,
      px_out_w, px_out_b, e_w, e_b,
      out, out + 60000);

  node_kernel<<<(N_NODES + 63) / 64, 256, 0, stream>>>(
      pos, feat, featb, wq, ph_b0, ph_b1, ph_b2,
      out, out + 60000);
}

// Round 7
// 507.428 us; speedup vs baseline: 8.7733x; 8.7400x over previous
//
#include <hip/hip_runtime.h>

#define N_NODES 20000
#define N_EDGES 640000
#define XS 136   // LDS activation row stride in bf16 units (128 + 8 pad)

#define INV_SQRT_AVG 0.0070714082f   // 1/sqrt(19999)
#define INV_AVG      5.000250e-5f    // 1/19999

#define FEATB_OFF 147456             // ushort offset of bf16 feat table in ws (after 9*16384 weights)

typedef __attribute__((ext_vector_type(8))) short bf16x8;
typedef __attribute__((ext_vector_type(4))) float f32x4;

__device__ __forceinline__ ushort f2b(float f) {
  unsigned x = __float_as_uint(f);
  unsigned r = (x + 0x7fffu + ((x >> 16) & 1u)) >> 16;   // RNE
  return (ushort)r;
}
__device__ __forceinline__ float silu(float v) { return v / (1.0f + __expf(-v)); }

// ---------------- prep: weights f32 [k][n] -> bf16 [n][k]; feat f32 -> bf16 ----
struct PrepArgs { const float* src[9]; };

__global__ __launch_bounds__(256) void prep_kernel(PrepArgs a, ushort* __restrict__ w) {
  int m = blockIdx.y;
  int i = blockIdx.x * 256 + threadIdx.x;   // 0..16383
  int k = i >> 7, n = i & 127;
  w[m * 16384 + n * 128 + k] = f2b(a.src[m][k * 128 + n]);
}

__global__ __launch_bounds__(256) void featcvt_kernel(const float* __restrict__ feat,
                                                      ushort* __restrict__ featb) {
  int i = blockIdx.x * 256 + threadIdx.x;   // exactly 2.56M threads
  featb[i] = f2b(feat[i]);
}

// ---------------- MFMA 64x32x128 per wave ----------------
__device__ __forceinline__ void gemm2(const ushort* X, const ushort* __restrict__ Wn0,
                                      int c, int q, f32x4 acc[4][2]) {
  const int kq = q * 8;
  bf16x8 b[2][4];
#pragma unroll
  for (int ct = 0; ct < 2; ++ct)
#pragma unroll
    for (int ks = 0; ks < 4; ++ks)
      b[ct][ks] = *(const bf16x8*)(Wn0 + (ct * 16 + c) * 128 + ks * 32 + kq);
#pragma unroll
  for (int mt = 0; mt < 4; ++mt)
#pragma unroll
    for (int ks = 0; ks < 4; ++ks) {
      bf16x8 a = *(const bf16x8*)(X + (mt * 16 + c) * XS + ks * 32 + kq);
      acc[mt][0] = __builtin_amdgcn_mfma_f32_16x16x32_bf16(a, b[0][ks], acc[mt][0], 0, 0, 0);
      acc[mt][1] = __builtin_amdgcn_mfma_f32_16x16x32_bf16(a, b[1][ks], acc[mt][1], 0, 0, 0);
    }
}

// stage one bf16 row from global into LDS (4 threads/row, 16B chunks)
__device__ __forceinline__ void stage_copy(ushort* X, const ushort* __restrict__ src,
                                           int row, int sub) {
  const bf16x8* s = (const bf16x8*)src;
  bf16x8* d = (bf16x8*)(X + row * XS);   // 272B row stride, 16B aligned
#pragma unroll
  for (int c2 = 0; c2 < 4; ++c2) d[sub + 4 * c2] = s[sub + 4 * c2];
}

// stage one f32 row (scaled) as bf16 into LDS
__device__ __forceinline__ void stage_cvt(ushort* X, const float* __restrict__ src,
                                          int row, int sub, float scale) {
  const float4* s4 = (const float4*)src + sub * 8;
  uint* d = (uint*)(X + row * XS + sub * 32);
#pragma unroll
  for (int i = 0; i < 8; ++i) {
    float4 v = s4[i];
    d[2 * i]     = (unsigned)f2b(v.x * scale) | ((unsigned)f2b(v.y * scale) << 16);
    d[2 * i + 1] = (unsigned)f2b(v.z * scale) | ((unsigned)f2b(v.w * scale) << 16);
  }
}

// ---------------- edge kernel ----------------
__global__ __launch_bounds__(256, 3) void edge_kernel(
    const float* __restrict__ pos, const ushort* __restrict__ featb,
    const int* __restrict__ snd, const int* __restrict__ rcv,
    const ushort* __restrict__ wq,
    const float* __restrict__ pe_w0, const float* __restrict__ pe_b0,
    const float* __restrict__ pe_b1,
    const float* __restrict__ px_b0, const float* __restrict__ px_b1,
    const float* __restrict__ px_out_w, const float* __restrict__ px_out_b,
    const float* __restrict__ e_w, const float* __restrict__ e_b,
    float* __restrict__ outv, float* __restrict__ outf) {
  __shared__ ushort XA[64 * XS];
  __shared__ ushort XB[64 * XS];
  __shared__ float lenf[64], gp[64], pp[64], egl[64];
  __shared__ float vec3[64][3];
  __shared__ int erc[64];

  const int tid = threadIdx.x;
  const int e0 = blockIdx.x * 64;
  const int lane = tid & 63;
  const int wv = tid >> 6;
  const int c = lane & 15, q = lane >> 4;
  const int n0 = wv * 32;
  const int col0 = n0 + c, col1 = col0 + 16;

  if (tid < 64) {
    int s = snd[e0 + tid], r = rcv[e0 + tid];
    erc[tid] = r;
    float vx = pos[r * 3 + 0] - pos[s * 3 + 0];
    float vy = pos[r * 3 + 1] - pos[s * 3 + 1];
    float vz = pos[r * 3 + 2] - pos[s * 3 + 2];
    float n2 = vx * vx + vy * vy + vz * vz;
    float L = (n2 > 0.0f) ? sqrtf(n2) : 0.0f;
    vec3[tid][0] = vx; vec3[tid][1] = vy; vec3[tid][2] = vz;
    lenf[tid] = L; gp[tid] = 0.0f; pp[tid] = 0.0f;
  }
  {
    int row = tid >> 2, sub = tid & 3;
    stage_copy(XA, featb + (size_t)snd[e0 + row] * 128, row, sub);
    stage_copy(XB, featb + (size_t)rcv[e0 + row] * 128, row, sub);
  }
  __syncthreads();

  const f32x4 z4 = {0.f, 0.f, 0.f, 0.f};
  f32x4 acc[4][2];
#pragma unroll
  for (int mt = 0; mt < 4; ++mt) { acc[mt][0] = z4; acc[mt][1] = z4; }

  // ---- phi_e layer 0 ----
  gemm2(XA, wq + 0 * 16384 + n0 * 128, c, q, acc);
  gemm2(XB, wq + 1 * 16384 + n0 * 128, c, q, acc);
  __syncthreads();
  {
    float b0 = pe_b0[col0], b1 = pe_b0[col1];
    float w0 = pe_w0[256 * 128 + col0], w1 = pe_w0[256 * 128 + col1];
#pragma unroll
    for (int mt = 0; mt < 4; ++mt)
#pragma unroll
      for (int rg = 0; rg < 4; ++rg) {
        int row = mt * 16 + q * 4 + rg;
        float L = lenf[row];
        XA[row * XS + col0] = f2b(silu(acc[mt][0][rg] + L * w0 + b0));
        XA[row * XS + col1] = f2b(silu(acc[mt][1][rg] + L * w1 + b1));
      }
  }
  __syncthreads();

  // ---- phi_e layer 1: XA -> m (single silu; keep m in regs across gate barrier) ----
#pragma unroll
  for (int mt = 0; mt < 4; ++mt) { acc[mt][0] = z4; acc[mt][1] = z4; }
  gemm2(XA, wq + 2 * 16384 + n0 * 128, c, q, acc);
  float mreg[4][4][2];
  {
    float b0 = pe_b1[col0], b1 = pe_b1[col1];
    float ew0 = e_w[col0], ew1 = e_w[col1];
#pragma unroll
    for (int mt = 0; mt < 4; ++mt)
#pragma unroll
      for (int rg = 0; rg < 4; ++rg) {
        int row = mt * 16 + q * 4 + rg;
        float m0 = silu(acc[mt][0][rg] + b0);
        float m1 = silu(acc[mt][1][rg] + b1);
        mreg[mt][rg][0] = m0; mreg[mt][rg][1] = m1;
        XB[row * XS + col0] = f2b(m0);
        XB[row * XS + col1] = f2b(m1);
        float rp = m0 * ew0 + m1 * ew1;
        rp += __shfl_xor(rp, 1); rp += __shfl_xor(rp, 2);
        rp += __shfl_xor(rp, 4); rp += __shfl_xor(rp, 8);
        if (c == 0) atomicAdd(&gp[row], rp);
      }
  }
  __syncthreads();
  if (tid < 64) egl[tid] = 1.0f / (1.0f + __expf(-(gp[tid] + e_b[0])));
  __syncthreads();

  // ---- gated m_i atomics, COALESCED layout (16 consecutive lanes per row) ----
#pragma unroll
  for (int mt = 0; mt < 4; ++mt)
#pragma unroll
    for (int rg = 0; rg < 4; ++rg) {
      int row = mt * 16 + q * 4 + rg;
      float eg = egl[row];
      size_t rb = (size_t)erc[row] * 128;
      atomicAdd(&outf[rb + col0], mreg[mt][rg][0] * eg);
      atomicAdd(&outf[rb + col1], mreg[mt][rg][1] * eg);
    }

  // ---- phi_x layer 0: XB -> XA (overlaps the atomics above) ----
#pragma unroll
  for (int mt = 0; mt < 4; ++mt) { acc[mt][0] = z4; acc[mt][1] = z4; }
  gemm2(XB, wq + 3 * 16384 + n0 * 128, c, q, acc);
  {
    float b0 = px_b0[col0], b1 = px_b0[col1];
#pragma unroll
    for (int mt = 0; mt < 4; ++mt)
#pragma unroll
      for (int rg = 0; rg < 4; ++rg) {
        int row = mt * 16 + q * 4 + rg;
        XA[row * XS + col0] = f2b(silu(acc[mt][0][rg] + b0));
        XA[row * XS + col1] = f2b(silu(acc[mt][1][rg] + b1));
      }
  }
  __syncthreads();

  // ---- phi_x layer 1: XA -> Dense(1) tail ----
#pragma unroll
  for (int mt = 0; mt < 4; ++mt) { acc[mt][0] = z4; acc[mt][1] = z4; }
  gemm2(XA, wq + 4 * 16384 + n0 * 128, c, q, acc);
  {
    float b0 = px_b1[col0], b1 = px_b1[col1];
    float pw0 = px_out_w[col0], pw1 = px_out_w[col1];
#pragma unroll
    for (int mt = 0; mt < 4; ++mt)
#pragma unroll
      for (int rg = 0; rg < 4; ++rg) {
        float rp = silu(acc[mt][0][rg] + b0) * pw0 + silu(acc[mt][1][rg] + b1) * pw1;
        rp += __shfl_xor(rp, 1); rp += __shfl_xor(rp, 2);
        rp += __shfl_xor(rp, 4); rp += __shfl_xor(rp, 8);
        if (c == 0) atomicAdd(&pp[mt * 16 + q * 4 + rg], rp);
      }
  }
  __syncthreads();
  if (tid < 192) {
    int ee = tid / 3, cc = tid - ee * 3;
    float phi = pp[ee] + px_out_b[0];
    float sh = phi * vec3[ee][cc] / (1.0f + lenf[ee]);
    atomicAdd(&outv[(size_t)erc[ee] * 3 + cc], sh);
  }
}

// ---------------- node kernel ----------------
__global__ __launch_bounds__(256, 3) void node_kernel(
    const float* __restrict__ pos, const float* __restrict__ feat,
    const ushort* __restrict__ featb, const ushort* __restrict__ wq,
    const float* __restrict__ ph_b0, const float* __restrict__ ph_b1,
    const float* __restrict__ ph_b2,
    float* __restrict__ outv, float* __restrict__ outf) {
  __shared__ ushort XA[64 * XS];
  __shared__ ushort XB[64 * XS];

  const int tid = threadIdx.x;
  const int nb0 = blockIdx.x * 64;
  const int lane = tid & 63;
  const int wv = tid >> 6;
  const int c = lane & 15, q = lane >> 4;
  const int n0 = wv * 32;
  const int col0 = n0 + c, col1 = col0 + 16;

  {
    int row = tid >> 2, sub = tid & 3;
    int nn = nb0 + row; if (nn >= N_NODES) nn = N_NODES - 1;
    stage_cvt(XA, outf + (size_t)nn * 128, row, sub, INV_SQRT_AVG);  // m_i
    stage_copy(XB, featb + (size_t)nn * 128, row, sub);
  }
  __syncthreads();

  const f32x4 z4 = {0.f, 0.f, 0.f, 0.f};
  f32x4 acc[4][2];
#pragma unroll
  for (int mt = 0; mt < 4; ++mt) { acc[mt][0] = z4; acc[mt][1] = z4; }

  // ---- ph layer 0: [m_i | feat] ----
  gemm2(XA, wq + 5 * 16384 + n0 * 128, c, q, acc);
  gemm2(XB, wq + 6 * 16384 + n0 * 128, c, q, acc);
  __syncthreads();
  {
    float b0 = ph_b0[col0], b1 = ph_b0[col1];
#pragma unroll
    for (int mt = 0; mt < 4; ++mt)
#pragma unroll
      for (int rg = 0; rg < 4; ++rg) {
        int row = mt * 16 + q * 4 + rg;
        XA[row * XS + col0] = f2b(silu(acc[mt][0][rg] + b0));
        XA[row * XS + col1] = f2b(silu(acc[mt][1][rg] + b1));
      }
  }
  __syncthreads();

  // ---- ph layer 1: XA -> XB ----
#pragma unroll
  for (int mt = 0; mt < 4; ++mt) { acc[mt][0] = z4; acc[mt][1] = z4; }
  gemm2(XA, wq + 7 * 16384 + n0 * 128, c, q, acc);
  __syncthreads();
  {
    float b0 = ph_b1[col0], b1 = ph_b1[col1];
#pragma unroll
    for (int mt = 0; mt < 4; ++mt)
#pragma unroll
      for (int rg = 0; rg < 4; ++rg) {
        int row = mt * 16 + q * 4 + rg;
        XB[row * XS + col0] = f2b(silu(acc[mt][0][rg] + b0));
        XB[row * XS + col1] = f2b(silu(acc[mt][1][rg] + b1));
      }
  }
  __syncthreads();

  // ---- ph layer 2 (no act) + residual ----
#pragma unroll
  for (int mt = 0; mt < 4; ++mt) { acc[mt][0] = z4; acc[mt][1] = z4; }
  gemm2(XB, wq + 8 * 16384 + n0 * 128, c, q, acc);
  {
    float b0 = ph_b2[col0], b1 = ph_b2[col1];
#pragma unroll
    for (int mt = 0; mt < 4; ++mt)
#pragma unroll
      for (int rg = 0; rg < 4; ++rg) {
        int row = mt * 16 + q * 4 + rg;
        int nn = nb0 + row;
        if (nn < N_NODES) {
          size_t o = (size_t)nn * 128;
          outf[o + col0] = acc[mt][0][rg] + b0 + feat[o + col0];
          outf[o + col1] = acc[mt][1][rg] + b1 + feat[o + col1];
        }
      }
  }
  if (tid < 192) {
    int nl = tid / 3, cc = tid - nl * 3;
    int nn = nb0 + nl;
    if (nn < N_NODES)
      outv[nn * 3 + cc] = pos[nn * 3 + cc] + outv[nn * 3 + cc] * INV_AVG;
  }
}

// ---------------- launch ----------------
extern "C" void kernel_launch(void* const* d_in, const int* in_sizes, int n_in,
                              void* d_out, int out_size, void* d_ws, size_t ws_size,
                              hipStream_t stream) {
  const float* pos  = (const float*)d_in[0];
  const float* feat = (const float*)d_in[1];
  const float* pe_w0 = (const float*)d_in[2];
  const float* pe_b0 = (const float*)d_in[3];
  const float* pe_b1 = (const float*)d_in[5];
  const float* px_b0 = (const float*)d_in[7];
  const float* px_b1 = (const float*)d_in[9];
  const float* px_out_w = (const float*)d_in[10];
  const float* px_out_b = (const float*)d_in[11];
  const float* e_w = (const float*)d_in[12];
  const float* e_b = (const float*)d_in[13];
  const float* ph_b0 = (const float*)d_in[15];
  const float* ph_b1 = (const float*)d_in[17];
  const float* ph_b2 = (const float*)d_in[19];
  const int* snd = (const int*)d_in[20];
  const int* rcv = (const int*)d_in[21];
  ushort* wq = (ushort*)d_ws;
  ushort* featb = wq + FEATB_OFF;
  float* out = (float*)d_out;

  // d_out doubles as accumulator (m_i in features region, shifts in vectors region)
  hipMemsetAsync(d_out, 0, (size_t)out_size * sizeof(float), stream);

  PrepArgs a;
  a.src[0] = pe_w0;
  a.src[1] = pe_w0 + 128 * 128;
  a.src[2] = (const float*)d_in[4];               // pe_w1
  a.src[3] = (const float*)d_in[6];               // px_w0
  a.src[4] = (const float*)d_in[8];               // px_w1
  a.src[5] = (const float*)d_in[14];              // ph_w0 (m_i half)
  a.src[6] = (const float*)d_in[14] + 128 * 128;  // ph_w0 (feat half)
  a.src[7] = (const float*)d_in[16];              // ph_w1
  a.src[8] = (const float*)d_in[18];              // ph_w2
  prep_kernel<<<dim3(64, 9), 256, 0, stream>>>(a, wq);
  featcvt_kernel<<<(N_NODES * 128) / 256, 256, 0, stream>>>(feat, featb);

  edge_kernel<<<N_EDGES / 64, 256, 0, stream>>>(
      pos, featb, snd, rcv, wq,
      pe_w0, pe_b0, pe_b1, px_b0, px_b1,
      px_out_w, px_out_b, e_w, e_b,
      out, out + 60000);

  node_kernel<<<(N_NODES + 63) / 64, 256, 0, stream>>>(
      pos, feat, featb, wq, ph_b0, ph_b1, ph_b2,
      out, out + 60000);
}

// Round 8
// 502.239 us; speedup vs baseline: 8.8639x; 1.0103x over previous
//
#include <hip/hip_runtime.h>

#define N_NODES 20000
#define N_EDGES 640000
#define XS 136   // LDS activation row stride in bf16 units (128 + 8 pad)

#define INV_SQRT_AVG 0.0070714082f   // 1/sqrt(19999)
#define INV_AVG      5.000250e-5f    // 1/19999

#define FEATB_OFF 147456             // ushort offset of bf16 feat table in ws (after 9*16384 weights)
#define OUT_FLOATS 2620000

typedef __attribute__((ext_vector_type(8))) short bf16x8;
typedef __attribute__((ext_vector_type(4))) float f32x4;

__device__ __forceinline__ ushort f2b(float f) {
  unsigned x = __float_as_uint(f);
  unsigned r = (x + 0x7fffu + ((x >> 16) & 1u)) >> 16;   // RNE
  return (ushort)r;
}
// fast silu: raw v_rcp_f32 (1 ulp) instead of IEEE division sequence
__device__ __forceinline__ float silu(float v) {
  return v * __builtin_amdgcn_rcpf(1.0f + __expf(-v));
}
__device__ __forceinline__ float sigmoid_fast(float v) {
  return __builtin_amdgcn_rcpf(1.0f + __expf(-v));
}

// ---------------- fused setup: weights f32[k][n]->bf16[n][k]; feat->bf16; zero out ----
struct PrepArgs { const float* src[9]; };

__global__ __launch_bounds__(256) void setup_kernel(PrepArgs a,
                                                    const float* __restrict__ feat,
                                                    ushort* __restrict__ wq,
                                                    ushort* __restrict__ featb,
                                                    float* __restrict__ out) {
  int i = blockIdx.x * 256 + threadIdx.x;
  if (i < OUT_FLOATS) out[i] = 0.0f;
  if (i < N_NODES * 128) featb[i] = f2b(feat[i]);
  if (i < 9 * 16384) {
    int m = i >> 14, idx = i & 16383;
    int k = idx >> 7, n = idx & 127;
    wq[m * 16384 + n * 128 + k] = f2b(a.src[m][k * 128 + n]);
  }
}

// ---------------- MFMA 64x32x128 per wave ----------------
__device__ __forceinline__ void gemm2(const ushort* X, const ushort* __restrict__ Wn0,
                                      int c, int q, f32x4 acc[4][2]) {
  const int kq = q * 8;
  bf16x8 b[2][4];
#pragma unroll
  for (int ct = 0; ct < 2; ++ct)
#pragma unroll
    for (int ks = 0; ks < 4; ++ks)
      b[ct][ks] = *(const bf16x8*)(Wn0 + (ct * 16 + c) * 128 + ks * 32 + kq);
#pragma unroll
  for (int mt = 0; mt < 4; ++mt)
#pragma unroll
    for (int ks = 0; ks < 4; ++ks) {
      bf16x8 a = *(const bf16x8*)(X + (mt * 16 + c) * XS + ks * 32 + kq);
      acc[mt][0] = __builtin_amdgcn_mfma_f32_16x16x32_bf16(a, b[0][ks], acc[mt][0], 0, 0, 0);
      acc[mt][1] = __builtin_amdgcn_mfma_f32_16x16x32_bf16(a, b[1][ks], acc[mt][1], 0, 0, 0);
    }
}

// stage one bf16 row from global into LDS (4 threads/row, 16B chunks)
__device__ __forceinline__ void stage_copy(ushort* X, const ushort* __restrict__ src,
                                           int row, int sub) {
  const bf16x8* s = (const bf16x8*)src;
  bf16x8* d = (bf16x8*)(X + row * XS);
#pragma unroll
  for (int c2 = 0; c2 < 4; ++c2) d[sub + 4 * c2] = s[sub + 4 * c2];
}

// stage one f32 row (scaled) as bf16 into LDS
__device__ __forceinline__ void stage_cvt(ushort* X, const float* __restrict__ src,
                                          int row, int sub, float scale) {
  const float4* s4 = (const float4*)src + sub * 8;
  uint* d = (uint*)(X + row * XS + sub * 32);
#pragma unroll
  for (int i = 0; i < 8; ++i) {
    float4 v = s4[i];
    d[2 * i]     = (unsigned)f2b(v.x * scale) | ((unsigned)f2b(v.y * scale) << 16);
    d[2 * i + 1] = (unsigned)f2b(v.z * scale) | ((unsigned)f2b(v.w * scale) << 16);
  }
}

// ---------------- edge kernel ----------------
__global__ __launch_bounds__(256, 3) void edge_kernel(
    const float* __restrict__ pos, const ushort* __restrict__ featb,
    const int* __restrict__ snd, const int* __restrict__ rcv,
    const ushort* __restrict__ wq,
    const float* __restrict__ pe_w0, const float* __restrict__ pe_b0,
    const float* __restrict__ pe_b1,
    const float* __restrict__ px_b0, const float* __restrict__ px_b1,
    const float* __restrict__ px_out_w, const float* __restrict__ px_out_b,
    const float* __restrict__ e_w, const float* __restrict__ e_b,
    float* __restrict__ outv, float* __restrict__ outf) {
  __shared__ ushort XA[64 * XS];
  __shared__ ushort XB[64 * XS];
  __shared__ float lenf[64], gp[64], pp[64], egl[64];
  __shared__ float vec3[64][3];
  __shared__ int erc[64];

  const int tid = threadIdx.x;
  const int e0 = blockIdx.x * 64;
  const int lane = tid & 63;
  const int wv = tid >> 6;
  const int c = lane & 15, q = lane >> 4;
  const int n0 = wv * 32;
  const int col0 = n0 + c, col1 = col0 + 16;

  if (tid < 64) {
    int s = snd[e0 + tid], r = rcv[e0 + tid];
    erc[tid] = r;
    float vx = pos[r * 3 + 0] - pos[s * 3 + 0];
    float vy = pos[r * 3 + 1] - pos[s * 3 + 1];
    float vz = pos[r * 3 + 2] - pos[s * 3 + 2];
    float n2 = vx * vx + vy * vy + vz * vz;
    float L = (n2 > 0.0f) ? sqrtf(n2) : 0.0f;
    vec3[tid][0] = vx; vec3[tid][1] = vy; vec3[tid][2] = vz;
    lenf[tid] = L; gp[tid] = 0.0f; pp[tid] = 0.0f;
  }
  {
    int row = tid >> 2, sub = tid & 3;
    stage_copy(XA, featb + (size_t)snd[e0 + row] * 128, row, sub);
    stage_copy(XB, featb + (size_t)rcv[e0 + row] * 128, row, sub);
  }
  __syncthreads();

  const f32x4 z4 = {0.f, 0.f, 0.f, 0.f};
  f32x4 acc[4][2];
#pragma unroll
  for (int mt = 0; mt < 4; ++mt) { acc[mt][0] = z4; acc[mt][1] = z4; }

  // ---- phi_e layer 0 ----
  gemm2(XA, wq + 0 * 16384 + n0 * 128, c, q, acc);
  gemm2(XB, wq + 1 * 16384 + n0 * 128, c, q, acc);
  __syncthreads();
  {
    float b0 = pe_b0[col0], b1 = pe_b0[col1];
    float w0 = pe_w0[256 * 128 + col0], w1 = pe_w0[256 * 128 + col1];
#pragma unroll
    for (int mt = 0; mt < 4; ++mt)
#pragma unroll
      for (int rg = 0; rg < 4; ++rg) {
        int row = mt * 16 + q * 4 + rg;
        float L = lenf[row];
        XA[row * XS + col0] = f2b(silu(acc[mt][0][rg] + L * w0 + b0));
        XA[row * XS + col1] = f2b(silu(acc[mt][1][rg] + L * w1 + b1));
      }
  }
  __syncthreads();

  // ---- phi_e layer 1: XA -> m (single silu; keep m in regs across gate barrier) ----
#pragma unroll
  for (int mt = 0; mt < 4; ++mt) { acc[mt][0] = z4; acc[mt][1] = z4; }
  gemm2(XA, wq + 2 * 16384 + n0 * 128, c, q, acc);
  float mreg[4][4][2];
  {
    float b0 = pe_b1[col0], b1 = pe_b1[col1];
    float ew0 = e_w[col0], ew1 = e_w[col1];
#pragma unroll
    for (int mt = 0; mt < 4; ++mt)
#pragma unroll
      for (int rg = 0; rg < 4; ++rg) {
        int row = mt * 16 + q * 4 + rg;
        float m0 = silu(acc[mt][0][rg] + b0);
        float m1 = silu(acc[mt][1][rg] + b1);
        mreg[mt][rg][0] = m0; mreg[mt][rg][1] = m1;
        XB[row * XS + col0] = f2b(m0);
        XB[row * XS + col1] = f2b(m1);
        float rp = m0 * ew0 + m1 * ew1;
        rp += __shfl_xor(rp, 1); rp += __shfl_xor(rp, 2);
        rp += __shfl_xor(rp, 4); rp += __shfl_xor(rp, 8);
        if (c == 0) atomicAdd(&gp[row], rp);
      }
  }
  __syncthreads();
  if (tid < 64) egl[tid] = sigmoid_fast(gp[tid] + e_b[0]);
  __syncthreads();

  // ---- gated m_i atomics, coalesced (16 consecutive lanes per row) ----
#pragma unroll
  for (int mt = 0; mt < 4; ++mt)
#pragma unroll
    for (int rg = 0; rg < 4; ++rg) {
      int row = mt * 16 + q * 4 + rg;
      float eg = egl[row];
      size_t rb = (size_t)erc[row] * 128;
      atomicAdd(&outf[rb + col0], mreg[mt][rg][0] * eg);
      atomicAdd(&outf[rb + col1], mreg[mt][rg][1] * eg);
    }

  // ---- phi_x layer 0: XB -> XA (overlaps the atomics above) ----
#pragma unroll
  for (int mt = 0; mt < 4; ++mt) { acc[mt][0] = z4; acc[mt][1] = z4; }
  gemm2(XB, wq + 3 * 16384 + n0 * 128, c, q, acc);
  {
    float b0 = px_b0[col0], b1 = px_b0[col1];
#pragma unroll
    for (int mt = 0; mt < 4; ++mt)
#pragma unroll
      for (int rg = 0; rg < 4; ++rg) {
        int row = mt * 16 + q * 4 + rg;
        XA[row * XS + col0] = f2b(silu(acc[mt][0][rg] + b0));
        XA[row * XS + col1] = f2b(silu(acc[mt][1][rg] + b1));
      }
  }
  __syncthreads();

  // ---- phi_x layer 1: XA -> Dense(1) tail ----
#pragma unroll
  for (int mt = 0; mt < 4; ++mt) { acc[mt][0] = z4; acc[mt][1] = z4; }
  gemm2(XA, wq + 4 * 16384 + n0 * 128, c, q, acc);
  {
    float b0 = px_b1[col0], b1 = px_b1[col1];
    float pw0 = px_out_w[col0], pw1 = px_out_w[col1];
#pragma unroll
    for (int mt = 0; mt < 4; ++mt)
#pragma unroll
      for (int rg = 0; rg < 4; ++rg) {
        float rp = silu(acc[mt][0][rg] + b0) * pw0 + silu(acc[mt][1][rg] + b1) * pw1;
        rp += __shfl_xor(rp, 1); rp += __shfl_xor(rp, 2);
        rp += __shfl_xor(rp, 4); rp += __shfl_xor(rp, 8);
        if (c == 0) atomicAdd(&pp[mt * 16 + q * 4 + rg], rp);
      }
  }
  __syncthreads();
  if (tid < 192) {
    int ee = tid / 3, cc = tid - ee * 3;
    float phi = pp[ee] + px_out_b[0];
    float sh = phi * vec3[ee][cc] * __builtin_amdgcn_rcpf(1.0f + lenf[ee]);
    atomicAdd(&outv[(size_t)erc[ee] * 3 + cc], sh);
  }
}

// ---------------- node kernel ----------------
__global__ __launch_bounds__(256, 3) void node_kernel(
    const float* __restrict__ pos, const float* __restrict__ feat,
    const ushort* __restrict__ featb, const ushort* __restrict__ wq,
    const float* __restrict__ ph_b0, const float* __restrict__ ph_b1,
    const float* __restrict__ ph_b2,
    float* __restrict__ outv, float* __restrict__ outf) {
  __shared__ ushort XA[64 * XS];
  __shared__ ushort XB[64 * XS];

  const int tid = threadIdx.x;
  const int nb0 = blockIdx.x * 64;
  const int lane = tid & 63;
  const int wv = tid >> 6;
  const int c = lane & 15, q = lane >> 4;
  const int n0 = wv * 32;
  const int col0 = n0 + c, col1 = col0 + 16;

  {
    int row = tid >> 2, sub = tid & 3;
    int nn = nb0 + row; if (nn >= N_NODES) nn = N_NODES - 1;
    stage_cvt(XA, outf + (size_t)nn * 128, row, sub, INV_SQRT_AVG);  // m_i
    stage_copy(XB, featb + (size_t)nn * 128, row, sub);
  }
  __syncthreads();

  const f32x4 z4 = {0.f, 0.f, 0.f, 0.f};
  f32x4 acc[4][2];
#pragma unroll
  for (int mt = 0; mt < 4; ++mt) { acc[mt][0] = z4; acc[mt][1] = z4; }

  // ---- ph layer 0: [m_i | feat] ----
  gemm2(XA, wq + 5 * 16384 + n0 * 128, c, q, acc);
  gemm2(XB, wq + 6 * 16384 + n0 * 128, c, q, acc);
  __syncthreads();
  {
    float b0 = ph_b0[col0], b1 = ph_b0[col1];
#pragma unroll
    for (int mt = 0; mt < 4; ++mt)
#pragma unroll
      for (int rg = 0; rg < 4; ++rg) {
        int row = mt * 16 + q * 4 + rg;
        XA[row * XS + col0] = f2b(silu(acc[mt][0][rg] + b0));
        XA[row * XS + col1] = f2b(silu(acc[mt][1][rg] + b1));
      }
  }
  __syncthreads();

  // ---- ph layer 1: XA -> XB ----
#pragma unroll
  for (int mt = 0; mt < 4; ++mt) { acc[mt][0] = z4; acc[mt][1] = z4; }
  gemm2(XA, wq + 7 * 16384 + n0 * 128, c, q, acc);
  __syncthreads();
  {
    float b0 = ph_b1[col0], b1 = ph_b1[col1];
#pragma unroll
    for (int mt = 0; mt < 4; ++mt)
#pragma unroll
      for (int rg = 0; rg < 4; ++rg) {
        int row = mt * 16 + q * 4 + rg;
        XB[row * XS + col0] = f2b(silu(acc[mt][0][rg] + b0));
        XB[row * XS + col1] = f2b(silu(acc[mt][1][rg] + b1));
      }
  }
  __syncthreads();

  // ---- ph layer 2 (no act) + residual ----
#pragma unroll
  for (int mt = 0; mt < 4; ++mt) { acc[mt][0] = z4; acc[mt][1] = z4; }
  gemm2(XB, wq + 8 * 16384 + n0 * 128, c, q, acc);
  {
    float b0 = ph_b2[col0], b1 = ph_b2[col1];
#pragma unroll
    for (int mt = 0; mt < 4; ++mt)
#pragma unroll
      for (int rg = 0; rg < 4; ++rg) {
        int row = mt * 16 + q * 4 + rg;
        int nn = nb0 + row;
        if (nn < N_NODES) {
          size_t o = (size_t)nn * 128;
          outf[o + col0] = acc[mt][0][rg] + b0 + feat[o + col0];
          outf[o + col1] = acc[mt][1][rg] + b1 + feat[o + col1];
        }
      }
  }
  if (tid < 192) {
    int nl = tid / 3, cc = tid - nl * 3;
    int nn = nb0 + nl;
    if (nn < N_NODES)
      outv[nn * 3 + cc] = pos[nn * 3 + cc] + outv[nn * 3 + cc] * INV_AVG;
  }
}

// ---------------- launch ----------------
extern "C" void kernel_launch(void* const* d_in, const int* in_sizes, int n_in,
                              void* d_out, int out_size, void* d_ws, size_t ws_size,
                              hipStream_t stream) {
  const float* pos  = (const float*)d_in[0];
  const float* feat = (const float*)d_in[1];
  const float* pe_w0 = (const float*)d_in[2];
  const float* pe_b0 = (const float*)d_in[3];
  const float* pe_b1 = (const float*)d_in[5];
  const float* px_b0 = (const float*)d_in[7];
  const float* px_b1 = (const float*)d_in[9];
  const float* px_out_w = (const float*)d_in[10];
  const float* px_out_b = (const float*)d_in[11];
  const float* e_w = (const float*)d_in[12];
  const float* e_b = (const float*)d_in[13];
  const float* ph_b0 = (const float*)d_in[15];
  const float* ph_b1 = (const float*)d_in[17];
  const float* ph_b2 = (const float*)d_in[19];
  const int* snd = (const int*)d_in[20];
  const int* rcv = (const int*)d_in[21];
  ushort* wq = (ushort*)d_ws;
  ushort* featb = wq + FEATB_OFF;
  float* out = (float*)d_out;

  PrepArgs a;
  a.src[0] = pe_w0;
  a.src[1] = pe_w0 + 128 * 128;
  a.src[2] = (const float*)d_in[4];               // pe_w1
  a.src[3] = (const float*)d_in[6];               // px_w0
  a.src[4] = (const float*)d_in[8];               // px_w1
  a.src[5] = (const float*)d_in[14];              // ph_w0 (m_i half)
  a.src[6] = (const float*)d_in[14] + 128 * 128;  // ph_w0 (feat half)
  a.src[7] = (const float*)d_in[16];              // ph_w1
  a.src[8] = (const float*)d_in[18];              // ph_w2

  // one fused setup launch: weight cvt + feat cvt + zero d_out (accumulators)
  setup_kernel<<<(OUT_FLOATS + 255) / 256, 256, 0, stream>>>(a, feat, wq, featb, out);

  edge_kernel<<<N_EDGES / 64, 256, 0, stream>>>(
      pos, featb, snd, rcv, wq,
      pe_w0, pe_b0, pe_b1, px_b0, px_b1,
      px_out_w, px_out_b, e_w, e_b,
      out, out + 60000);

  node_kernel<<<(N_NODES + 63) / 64, 256, 0, stream>>>(
      pos, feat, featb, wq, ph_b0, ph_b1, ph_b2,
      out, out + 60000);
}